// Round 17
// baseline (102.418 us; speedup 1.0000x reference)
//
#include <hip/hip_runtime.h>
#include <hip/hip_bf16.h>

// Block-sparse attention: B=2, S=4096, H=16, D=128, BS=64, LOCAL=8, GLOBAL=1.
// fp32 in/out, bf16 MFMA, flash softmax in exp2 domain (static max).
// Round 17 (base r16 = 97.4us): PV-deferred pipeline. PV(t) runs in iter t+1
// merged with QK(t+1) into one 32-MFMA cluster (independent -> LDS reads of
// both pipeline against MFMA issue). Kb/Vt double-buffered (64KB; blocks/CU
// unchanged at 2, register-pinned). paf carried across the barrier.
//   iter t: [QK(t) || PV(t-1)] -> softmax(t)->paf -> B_mid ->
//           stage K/V(t+1) into buf c^1 (reads issued iter t-1) -> B_end.

typedef __bf16 bf16_t;
typedef bf16_t bf16x8 __attribute__((ext_vector_type(8)));
typedef bf16_t bf16x4 __attribute__((ext_vector_type(4)));
typedef float f32x4 __attribute__((ext_vector_type(4)));
typedef uint32_t u32x4 __attribute__((ext_vector_type(4)));

#define BSZ 64
#define DIM 128
#define NH 16
#define SEQ 4096
#define ROWSTRIDE (NH * DIM)

// LDS barrier with lgkm-only drain (global loads may stay in flight).
#define LGKM_BARRIER()                                          \
    do {                                                        \
        asm volatile("s_waitcnt lgkmcnt(0)" ::: "memory");      \
        __builtin_amdgcn_s_barrier();                           \
        __builtin_amdgcn_sched_barrier(0);                      \
    } while (0)

// Kb: [64][128] bf16 per buffer, A = row*256 + col*2 (A < 16384).
__device__ __forceinline__ uint32_t kb_swz(uint32_t A) {
    return A ^ (((A >> 8) & 7u) << 4);
}
// Vt: [128][64] bf16 per buffer, A = d*128 + k*2 (A < 16384).
__device__ __forceinline__ uint32_t vt_swz(uint32_t A) {
    return A ^ (((A >> 9) & 7u) << 4) ^ (((A >> 8) & 1u) << 6);
}

__global__ __launch_bounds__(256) void sparse_attn_kernel(
    const float* __restrict__ q, const float* __restrict__ k,
    const float* __restrict__ v, float* __restrict__ out)
{
    __shared__ __align__(16) bf16_t Kb[2 * BSZ * DIM];   // 32768 B
    __shared__ __align__(16) bf16_t Vt[2 * DIM * BSZ];   // 32768 B (total 65536)

    // XCD-aware swizzle: 2048 wgs, 8 XCDs -> contiguous 256-chunk per XCD.
    const int L  = ((blockIdx.x & 7) << 8) | (blockIdx.x >> 3);
    const int qi = L & 63;
    const int h  = (L >> 6) & 15;
    const int b  = L >> 10;

    const int tid  = threadIdx.x;
    const int wave = tid >> 6;
    const int lane = tid & 63;
    const int lr = lane & 15;
    const int lk = lane >> 4;
    const int k0 = lk * 8;

    const int sc4 = tid & 31;   // staging: float4 column 0..31
    const int sr  = tid >> 5;   // staging: row group 0..7

    const float scale2 = 0.12751649736230476f;  // (1/sqrt(128)) * log2(e)

    const size_t bh_off = ((size_t)b * SEQ * NH + (size_t)h) * DIM;
    const float* kbh = k + bh_off;
    const float* vbh = v + bh_off;

    // ---- Q fragments, pre-scaled (wave owns q rows [qi*64+wave*16, +16)) ----
    bf16x8 qf[4];
    {
        const float* qrow = q + bh_off + (size_t)(qi * 64 + wave * 16 + lr) * ROWSTRIDE;
        #pragma unroll
        for (int kk = 0; kk < 4; ++kk) {
            const float4 a0 = *(const float4*)(qrow + 32 * kk + k0);
            const float4 a1 = *(const float4*)(qrow + 32 * kk + k0 + 4);
            bf16x8 f;
            f[0] = (bf16_t)(a0.x * scale2); f[1] = (bf16_t)(a0.y * scale2);
            f[2] = (bf16_t)(a0.z * scale2); f[3] = (bf16_t)(a0.w * scale2);
            f[4] = (bf16_t)(a1.x * scale2); f[5] = (bf16_t)(a1.y * scale2);
            f[6] = (bf16_t)(a1.z * scale2); f[7] = (bf16_t)(a1.w * scale2);
            qf[kk] = f;
        }
    }

    f32x4 oacc[8];
    #pragma unroll
    for (int n = 0; n < 8; ++n) oacc[n] = (f32x4){0.f, 0.f, 0.f, 0.f};
    float lrun = 0.f;   // per-lane partial row-sum; this lane's q-row is lr

    const int qrow_local = wave * 16 + lr;  // q position within the 64-block
    const int nnz = (qi < 8) ? (qi + 1) : 9;

    // ---- push-exchange addressing (constant per lane) ----
    const int bit0 = lk & 1;
    const int bit1 = lk >> 1;
    const bool hi  = (lk & 2) != 0;
    const int Dlo  = (lr + 16 * bit1) << 2;
    const int Dhi  = Dlo + (32 << 2);
    const int addrA = bit0 ? Dhi : Dlo;
    const int addrB = bit0 ? Dlo : Dhi;

    float4 kreg[8];
    float4 vreg[8];

    #define LOAD_K(jb)                                                            \
    {                                                                             \
        const float* kb_ = kbh + (size_t)((jb) * 64) * ROWSTRIDE + 4 * sc4;       \
        _Pragma("unroll")                                                         \
        for (int i = 0; i < 8; ++i)                                               \
            kreg[i] = *(const float4*)(kb_ + (size_t)(8 * i + sr) * ROWSTRIDE);   \
    }
    #define LOAD_V(jb)                                                            \
    {                                                                             \
        const float* vb_ = vbh + (size_t)((jb) * 64) * ROWSTRIDE + 4 * sc4;       \
        _Pragma("unroll")                                                         \
        for (int T = 0; T < 2; ++T)                                               \
            _Pragma("unroll")                                                     \
            for (int i = 0; i < 4; ++i)                                           \
                vreg[T * 4 + i] = *(const float4*)(vb_ +                          \
                    (size_t)(4 * (sr + 8 * T) + i) * ROWSTRIDE);                  \
    }
    #define KB_WRITE(cc)                                                          \
    {                                                                             \
        _Pragma("unroll")                                                         \
        for (int i = 0; i < 8; ++i) {                                             \
            const float4 t4 = kreg[i];                                            \
            bf16x4 cq = {(bf16_t)t4.x, (bf16_t)t4.y, (bf16_t)t4.z, (bf16_t)t4.w};\
            const uint32_t A = kb_swz((uint32_t)((8 * i + sr) * 256 + 8 * sc4));  \
            *(bf16x4*)((char*)Kb + (cc) * 16384 + A) = cq;                        \
        }                                                                         \
    }
    #define VT_WRITE(cc)                                                          \
    {                                                                             \
        _Pragma("unroll")                                                         \
        for (int T = 0; T < 2; ++T) {                                             \
            _Pragma("unroll")                                                     \
            for (int j2 = 0; j2 < 4; ++j2) {                                      \
                const int d = 4 * sc4 + j2;                                       \
                bf16x4 cq = {(bf16_t)((const float*)&vreg[T * 4 + 0])[j2],        \
                             (bf16_t)((const float*)&vreg[T * 4 + 1])[j2],        \
                             (bf16_t)((const float*)&vreg[T * 4 + 2])[j2],        \
                             (bf16_t)((const float*)&vreg[T * 4 + 3])[j2]};       \
                const uint32_t A = vt_swz((uint32_t)(d * 128 + 8 * (sr + 8 * T)));\
                *(bf16x4*)((char*)Vt + (cc) * 16384 + A) = cq;                    \
            }                                                                     \
        }                                                                         \
    }

    // ---- prologue: stage tile 0 into buf 0; prefetch tile 1 into regs ----
    LOAD_K(0);
    LOAD_V(0);
    KB_WRITE(0);
    VT_WRITE(0);
    if (nnz > 1) {
        const int j1 = (qi < 8) ? 1 : (qi - 7);
        LOAD_K(j1);
        LOAD_V(j1);
    }
    LGKM_BARRIER();

    bf16x8 paf[2];

    for (int t = 0; t < nnz; ++t) {
        const int j = (qi < 8) ? t : ((t == 0) ? 0 : (qi - 8 + t));
        const int c = t & 1;
        const uint32_t kOff = (uint32_t)(c * 16384);
        const uint32_t vOffPrev = (uint32_t)((c ^ 1) * 16384);

        // ---- merged MFMA cluster: QK(t) from Kb[c]  ||  PV(t-1) from Vt[c^1] --
        f32x4 sacc[4];
        __builtin_amdgcn_s_setprio(1);
        #pragma unroll
        for (int n = 0; n < 4; ++n) {
            f32x4 a = (f32x4){0.f, 0.f, 0.f, 0.f};
            #pragma unroll
            for (int kk = 0; kk < 4; ++kk) {
                const uint32_t A = kb_swz((uint32_t)((16 * n + lr) * 256 + 64 * kk + 16 * lk));
                bf16x8 kf = *(const bf16x8*)((const char*)Kb + kOff + A);
                a = __builtin_amdgcn_mfma_f32_16x16x32_bf16(kf, qf[kk], a, 0, 0, 0);
            }
            sacc[n] = a;
        }
        if (t > 0) {
            #pragma unroll
            for (int n = 0; n < 8; ++n) {
                f32x4 a = oacc[n];
                #pragma unroll
                for (int kk = 0; kk < 2; ++kk) {
                    const uint32_t Av = vt_swz((uint32_t)((16 * n + lr) * 128 + 64 * kk + 16 * lk));
                    bf16x8 vf = *(const bf16x8*)((const char*)Vt + vOffPrev + Av);
                    a = __builtin_amdgcn_mfma_f32_16x16x32_bf16(paf[kk], vf, a, 0, 0, 0);
                }
                oacc[n] = a;
            }
        }
        __builtin_amdgcn_s_setprio(0);

        // ---- mask (diag only) ----
        if (j == qi) {
            #pragma unroll
            for (int n = 0; n < 4; ++n)
                #pragma unroll
                for (int r = 0; r < 4; ++r) {
                    if (16 * n + 4 * lk + r > qrow_local) sacc[n][r] = -1.0e30f;
                }
        }

        // ---- static-max softmax: p = 2^s directly (scale-invariant) ----
        uint32_t ch[8];
        #pragma unroll
        for (int n = 0; n < 4; ++n) {
            float p0 = exp2f(sacc[n][0]);
            float p1 = exp2f(sacc[n][1]);
            float p2 = exp2f(sacc[n][2]);
            float p3 = exp2f(sacc[n][3]);
            lrun += (p0 + p1) + (p2 + p3);
            bf16x4 c4 = {(bf16_t)p0, (bf16_t)p1, (bf16_t)p2, (bf16_t)p3};
            uint32_t* cw = (uint32_t*)&c4;
            ch[2 * n]     = cw[0];
            ch[2 * n + 1] = cw[1];
        }

        // ---- push-model exchange: paf[kk] = P[q=lr][k=32kk+8lk..+7] ----
        #pragma unroll
        for (int kk = 0; kk < 2; ++kk) {
            uint32_t r0 = (uint32_t)__builtin_amdgcn_ds_permute(
                addrA, (int)(bit0 ? ch[4 * kk + 2] : ch[4 * kk + 0]));
            uint32_t r1 = (uint32_t)__builtin_amdgcn_ds_permute(
                addrA, (int)(bit0 ? ch[4 * kk + 3] : ch[4 * kk + 1]));
            uint32_t r2 = (uint32_t)__builtin_amdgcn_ds_permute(
                addrB, (int)(bit0 ? ch[4 * kk + 0] : ch[4 * kk + 2]));
            uint32_t r3 = (uint32_t)__builtin_amdgcn_ds_permute(
                addrB, (int)(bit0 ? ch[4 * kk + 1] : ch[4 * kk + 3]));
            u32x4 tv = {hi ? r2 : r0, hi ? r3 : r1,
                        hi ? r0 : r2, hi ? r1 : r3};
            paf[kk] = *(bf16x8*)&tv;
        }

        LGKM_BARRIER();   // B_mid: Kb[c] + Vt[c^1] reads of this iter done

        // ---- stage tile t+1 into buf c^1; issue loads for t+2 ----
        if (t + 1 < nnz) {
            KB_WRITE(c ^ 1);
            VT_WRITE(c ^ 1);
            if (t + 2 < nnz) {
                const int j2n = (qi < 8) ? (t + 2) : (qi - 8 + t + 2);
                LOAD_K(j2n);
                LOAD_V(j2n);
            }
            LGKM_BARRIER();   // B_end: publish K/V(t+1)
        }
    }

    // ---- epilogue: final PV(nnz-1), l reduce, store ----
    {
        const uint32_t vOffLast = (uint32_t)(((nnz - 1) & 1) * 16384);
        __builtin_amdgcn_s_setprio(1);
        #pragma unroll
        for (int n = 0; n < 8; ++n) {
            f32x4 a = oacc[n];
            #pragma unroll
            for (int kk = 0; kk < 2; ++kk) {
                const uint32_t Av = vt_swz((uint32_t)((16 * n + lr) * 128 + 64 * kk + 16 * lk));
                bf16x8 vf = *(const bf16x8*)((const char*)Vt + vOffLast + Av);
                a = __builtin_amdgcn_mfma_f32_16x16x32_bf16(paf[kk], vf, a, 0, 0, 0);
            }
            oacc[n] = a;
        }
        __builtin_amdgcn_s_setprio(0);
    }

    float lrtot = lrun;
    lrtot += __shfl_xor(lrtot, 16);
    lrtot += __shfl_xor(lrtot, 32);
    float* obase = out + bh_off + (size_t)(qi * 64 + wave * 16) * ROWSTRIDE;
    #pragma unroll
    for (int r = 0; r < 4; ++r) {
        const float inv = 1.0f / __shfl(lrtot, 4 * lk + r);
        float* orow = obase + (size_t)(4 * lk + r) * ROWSTRIDE;
        #pragma unroll
        for (int n = 0; n < 8; ++n) {
            orow[16 * n + lr] = oacc[n][r] * inv;
        }
    }
}

extern "C" void kernel_launch(void* const* d_in, const int* in_sizes, int n_in,
                              void* d_out, int out_size, void* d_ws, size_t ws_size,
                              hipStream_t stream) {
    const float* q = (const float*)d_in[0];
    const float* k = (const float*)d_in[1];
    const float* v = (const float*)d_in[2];
    float* out = (float*)d_out;
    sparse_attn_kernel<<<dim3(2048), dim3(256), 0, stream>>>(q, k, v, out);
}

// Round 18
// 97.712 us; speedup vs baseline: 1.0482x; 1.0482x over previous
//
#include <hip/hip_runtime.h>
#include <hip/hip_bf16.h>

// Block-sparse attention: B=2, S=4096, H=16, D=128, BS=64, LOCAL=8, GLOBAL=1.
// fp32 in/out, bf16 MFMA, flash softmax in exp2 domain (static max).
// Round 18 (base r16 = 97.4us, best): remove sched_barrier(0) from the
// barrier macro. The "memory"-clobbered s_waitcnt asm + s_barrier already
// order all memory ops; the extra sched_barrier(0) pinned ALL code motion,
// blocking the scheduler from hoisting next-tile address math / global-load
// issue across barriers. (Rule #18's hazard needs inline-asm ds_read with
// invisible deps — ours are compiler-visible loads.)

typedef __bf16 bf16_t;
typedef bf16_t bf16x8 __attribute__((ext_vector_type(8)));
typedef bf16_t bf16x4 __attribute__((ext_vector_type(4)));
typedef float f32x4 __attribute__((ext_vector_type(4)));
typedef uint32_t u32x4 __attribute__((ext_vector_type(4)));

#define BSZ 64
#define DIM 128
#define NH 16
#define SEQ 4096
#define ROWSTRIDE (NH * DIM)

// LDS barrier with lgkm-only drain (global loads may stay in flight).
#define LGKM_BARRIER()                                          \
    do {                                                        \
        asm volatile("s_waitcnt lgkmcnt(0)" ::: "memory");      \
        __builtin_amdgcn_s_barrier();                           \
    } while (0)

// Kb: [64][128] bf16, A = row*256 + col*2. Fold row low-3 bits into chunk bits.
__device__ __forceinline__ uint32_t kb_swz(uint32_t A) {
    return A ^ (((A >> 8) & 7u) << 4);
}
// Vt: [128][64] bf16, A = d*128 + k*2. Fold d bits so PV read (lanes vary d)
// spreads over 8 chunk slots per 16-lane phase.
__device__ __forceinline__ uint32_t vt_swz(uint32_t A) {
    return A ^ (((A >> 9) & 7u) << 4) ^ (((A >> 8) & 1u) << 6);
}

__global__ __launch_bounds__(256) void sparse_attn_kernel(
    const float* __restrict__ q, const float* __restrict__ k,
    const float* __restrict__ v, float* __restrict__ out)
{
    __shared__ __align__(16) bf16_t Kb[BSZ * DIM];      // 16384 B
    __shared__ __align__(16) bf16_t Vt[DIM * BSZ];      // 16384 B (total 32768)

    // XCD-aware swizzle: 2048 wgs, 8 XCDs -> contiguous 256-chunk per XCD.
    const int L  = ((blockIdx.x & 7) << 8) | (blockIdx.x >> 3);
    const int qi = L & 63;
    const int h  = (L >> 6) & 15;
    const int b  = L >> 10;

    const int tid  = threadIdx.x;
    const int wave = tid >> 6;
    const int lane = tid & 63;
    const int lr = lane & 15;
    const int lk = lane >> 4;
    const int k0 = lk * 8;

    const int sc4 = tid & 31;   // staging: float4 column 0..31
    const int sr  = tid >> 5;   // staging: row group 0..7

    const float scale2 = 0.12751649736230476f;  // (1/sqrt(128)) * log2(e)

    const size_t bh_off = ((size_t)b * SEQ * NH + (size_t)h) * DIM;
    const float* kbh = k + bh_off;
    const float* vbh = v + bh_off;

    // ---- Q fragments, pre-scaled (wave owns q rows [qi*64+wave*16, +16)) ----
    bf16x8 qf[4];
    {
        const float* qrow = q + bh_off + (size_t)(qi * 64 + wave * 16 + lr) * ROWSTRIDE;
        #pragma unroll
        for (int kk = 0; kk < 4; ++kk) {
            const float4 a0 = *(const float4*)(qrow + 32 * kk + k0);
            const float4 a1 = *(const float4*)(qrow + 32 * kk + k0 + 4);
            bf16x8 f;
            f[0] = (bf16_t)(a0.x * scale2); f[1] = (bf16_t)(a0.y * scale2);
            f[2] = (bf16_t)(a0.z * scale2); f[3] = (bf16_t)(a0.w * scale2);
            f[4] = (bf16_t)(a1.x * scale2); f[5] = (bf16_t)(a1.y * scale2);
            f[6] = (bf16_t)(a1.z * scale2); f[7] = (bf16_t)(a1.w * scale2);
            qf[kk] = f;
        }
    }

    f32x4 oacc[8];
    #pragma unroll
    for (int n = 0; n < 8; ++n) oacc[n] = (f32x4){0.f, 0.f, 0.f, 0.f};
    float lrun = 0.f;   // per-lane partial row-sum; this lane's q-row is lr

    const int qrow_local = wave * 16 + lr;  // q position within the 64-block
    const int nnz = (qi < 8) ? (qi + 1) : 9;

    // ---- push-exchange addressing (constant per lane) ----
    const int bit0 = lk & 1;
    const int bit1 = lk >> 1;
    const bool hi  = (lk & 2) != 0;
    const int Dlo  = (lr + 16 * bit1) << 2;   // dest-lane*4, hi_t = 0
    const int Dhi  = Dlo + (32 << 2);         // hi_t = 1
    const int addrA = bit0 ? Dhi : Dlo;       // instrs j = 0,1
    const int addrB = bit0 ? Dlo : Dhi;       // instrs j = 2,3

    float4 kreg[8];   // K row (8i+sr), cols 4*sc4..+3   (one iter ahead)
    float4 vreg[8];   // V row 4*(sr+8*T)+i, cols 4*sc4..+3  (one iter ahead)

    #define LOAD_K(jb)                                                            \
    {                                                                             \
        const float* kb_ = kbh + (size_t)((jb) * 64) * ROWSTRIDE + 4 * sc4;       \
        _Pragma("unroll")                                                         \
        for (int i = 0; i < 8; ++i)                                               \
            kreg[i] = *(const float4*)(kb_ + (size_t)(8 * i + sr) * ROWSTRIDE);   \
    }
    #define LOAD_V(jb)                                                            \
    {                                                                             \
        const float* vb_ = vbh + (size_t)((jb) * 64) * ROWSTRIDE + 4 * sc4;       \
        _Pragma("unroll")                                                         \
        for (int T = 0; T < 2; ++T)                                               \
            _Pragma("unroll")                                                     \
            for (int i = 0; i < 4; ++i)                                           \
                vreg[T * 4 + i] = *(const float4*)(vb_ +                          \
                    (size_t)(4 * (sr + 8 * T) + i) * ROWSTRIDE);                  \
    }

    LOAD_K(0);  // j_of(0) == 0 for every qi
    LOAD_V(0);

    for (int t = 0; t < nnz; ++t) {
        const int j = (qi < 8) ? t : ((t == 0) ? 0 : (qi - 8 + t));
        const int jn = (qi < 8) ? (t + 1) : (qi - 8 + t + 1);
        const bool have_next = (t + 1 < nnz);

        // ---- Kb write from kreg (vmcnt waits only these K loads) ----
        #pragma unroll
        for (int i = 0; i < 8; ++i) {
            const float4 t4 = kreg[i];
            bf16x4 c = {(bf16_t)t4.x, (bf16_t)t4.y, (bf16_t)t4.z, (bf16_t)t4.w};
            const uint32_t A = kb_swz((uint32_t)((8 * i + sr) * 256 + 8 * sc4));
            *(bf16x4*)((char*)Kb + A) = c;
        }
        // ---- kreg dead: issue next K loads NOW (full-iter cover) ----
        if (have_next) { LOAD_K(jn); }

        LGKM_BARRIER();   // Kb visible; K(t+1)/V(t) loads stay in flight

        // ---- S^T = K*Q^T: lane holds S[k=16n+4lk+r][q=lr] (exp2 domain) ----
        f32x4 sacc[4];
        __builtin_amdgcn_s_setprio(1);
        #pragma unroll
        for (int n = 0; n < 4; ++n) {
            f32x4 a = (f32x4){0.f, 0.f, 0.f, 0.f};
            #pragma unroll
            for (int kk = 0; kk < 4; ++kk) {
                const uint32_t A = kb_swz((uint32_t)((16 * n + lr) * 256 + 64 * kk + 16 * lk));
                bf16x8 kf = *(const bf16x8*)((const char*)Kb + A);
                a = __builtin_amdgcn_mfma_f32_16x16x32_bf16(kf, qf[kk], a, 0, 0, 0);
            }
            sacc[n] = a;
        }
        __builtin_amdgcn_s_setprio(0);

        // ---- Vt write from vreg (vmcnt waits the V loads; full-iter cover) --
        #pragma unroll
        for (int T = 0; T < 2; ++T) {
            #pragma unroll
            for (int j2 = 0; j2 < 4; ++j2) {
                const int d = 4 * sc4 + j2;
                bf16x4 c = {(bf16_t)((const float*)&vreg[T * 4 + 0])[j2],
                            (bf16_t)((const float*)&vreg[T * 4 + 1])[j2],
                            (bf16_t)((const float*)&vreg[T * 4 + 2])[j2],
                            (bf16_t)((const float*)&vreg[T * 4 + 3])[j2]};
                const uint32_t A = vt_swz((uint32_t)(d * 128 + 8 * (sr + 8 * T)));
                *(bf16x4*)((char*)Vt + A) = c;
            }
        }
        // ---- vreg dead: issue next V loads NOW (full-iter cover) ----
        if (have_next) { LOAD_V(jn); }

        // ---- mask (diag only) ----
        if (j == qi) {
            #pragma unroll
            for (int n = 0; n < 4; ++n)
                #pragma unroll
                for (int r = 0; r < 4; ++r) {
                    if (16 * n + 4 * lk + r > qrow_local) sacc[n][r] = -1.0e30f;
                }
        }

        // ---- static-max softmax: p = 2^s directly (scale-invariant) ----
        uint32_t ch[8];
        #pragma unroll
        for (int n = 0; n < 4; ++n) {
            float p0 = exp2f(sacc[n][0]);
            float p1 = exp2f(sacc[n][1]);
            float p2 = exp2f(sacc[n][2]);
            float p3 = exp2f(sacc[n][3]);
            lrun += (p0 + p1) + (p2 + p3);
            bf16x4 c4 = {(bf16_t)p0, (bf16_t)p1, (bf16_t)p2, (bf16_t)p3};
            uint32_t* cw = (uint32_t*)&c4;
            ch[2 * n]     = cw[0];
            ch[2 * n + 1] = cw[1];
        }

        // ---- push-model exchange: paf[kk] = P[q=lr][k=32kk+8lk..+7] ----
        // instr j: even-d srcs push ch[4kk+j], odd-d srcs push ch[4kk+(j^2)];
        // dests: j<2 -> addrA, j>=2 -> addrB. Dest word map: w0=r[2hi],
        // w1=r[2hi+1], w2=r[2-2hi], w3=r[3-2hi].  (hand-verified vs r8 pull)
        bf16x8 paf[2];
        #pragma unroll
        for (int kk = 0; kk < 2; ++kk) {
            uint32_t r0 = (uint32_t)__builtin_amdgcn_ds_permute(
                addrA, (int)(bit0 ? ch[4 * kk + 2] : ch[4 * kk + 0]));
            uint32_t r1 = (uint32_t)__builtin_amdgcn_ds_permute(
                addrA, (int)(bit0 ? ch[4 * kk + 3] : ch[4 * kk + 1]));
            uint32_t r2 = (uint32_t)__builtin_amdgcn_ds_permute(
                addrB, (int)(bit0 ? ch[4 * kk + 0] : ch[4 * kk + 2]));
            uint32_t r3 = (uint32_t)__builtin_amdgcn_ds_permute(
                addrB, (int)(bit0 ? ch[4 * kk + 1] : ch[4 * kk + 3]));
            u32x4 tv = {hi ? r2 : r0, hi ? r3 : r1,
                        hi ? r0 : r2, hi ? r1 : r3};
            paf[kk] = *(bf16x8*)&tv;
        }

        LGKM_BARRIER();   // Vt visible + this wave's Kb reads done

        // ---- O += P * V ----
        __builtin_amdgcn_s_setprio(1);
        #pragma unroll
        for (int n = 0; n < 8; ++n) {
            f32x4 a = oacc[n];
            #pragma unroll
            for (int kk = 0; kk < 2; ++kk) {
                const uint32_t Av = vt_swz((uint32_t)((16 * n + lr) * 128 + 64 * kk + 16 * lk));
                bf16x8 vf = *(const bf16x8*)((const char*)Vt + Av);
                a = __builtin_amdgcn_mfma_f32_16x16x32_bf16(paf[kk], vf, a, 0, 0, 0);
            }
            oacc[n] = a;
        }
        __builtin_amdgcn_s_setprio(0);
    }

    // ---- epilogue: total l per q-row, redistribute to oacc rows, store ----
    float lrtot = lrun;
    lrtot += __shfl_xor(lrtot, 16);
    lrtot += __shfl_xor(lrtot, 32);
    float* obase = out + bh_off + (size_t)(qi * 64 + wave * 16) * ROWSTRIDE;
    #pragma unroll
    for (int r = 0; r < 4; ++r) {
        const float inv = 1.0f / __shfl(lrtot, 4 * lk + r);
        float* orow = obase + (size_t)(4 * lk + r) * ROWSTRIDE;
        #pragma unroll
        for (int n = 0; n < 8; ++n) {
            orow[16 * n + lr] = oacc[n][r] * inv;
        }
    }
}

extern "C" void kernel_launch(void* const* d_in, const int* in_sizes, int n_in,
                              void* d_out, int out_size, void* d_ws, size_t ws_size,
                              hipStream_t stream) {
    const float* q = (const float*)d_in[0];
    const float* k = (const float*)d_in[1];
    const float* v = (const float*)d_in[2];
    float* out = (float*)d_out;
    sparse_attn_kernel<<<dim3(2048), dim3(256), 0, stream>>>(q, k, v, out);
}

// Round 19
// 96.462 us; speedup vs baseline: 1.0617x; 1.0130x over previous
//
#include <hip/hip_runtime.h>
#include <hip/hip_bf16.h>

// Block-sparse attention: B=2, S=4096, H=16, D=128, BS=64, LOCAL=8, GLOBAL=1.
// fp32 in/out, bf16 MFMA, flash softmax in exp2 domain (static max).
// Round 19 (base r18 = 97.4us): b128 staging writes (layout-invariant).
//  - K: 16 threads/row load 8 contiguous floats -> one bf16x8 b128 write
//    (4 writes/thread, was 8 b64). Kb byte layout identical; QK unchanged.
//  - V: thread loads float4 from 8 consecutive rows -> transposed column
//    write packs 8 contiguous k into one b128 (4 writes, was 8 b64).
//  LDS write-instruction count halved; read paths untouched; banks balanced.

typedef __bf16 bf16_t;
typedef bf16_t bf16x8 __attribute__((ext_vector_type(8)));
typedef bf16_t bf16x4 __attribute__((ext_vector_type(4)));
typedef float f32x4 __attribute__((ext_vector_type(4)));
typedef uint32_t u32x4 __attribute__((ext_vector_type(4)));

#define BSZ 64
#define DIM 128
#define NH 16
#define SEQ 4096
#define ROWSTRIDE (NH * DIM)

// LDS barrier with lgkm-only drain (global loads may stay in flight).
#define LGKM_BARRIER()                                          \
    do {                                                        \
        asm volatile("s_waitcnt lgkmcnt(0)" ::: "memory");      \
        __builtin_amdgcn_s_barrier();                           \
    } while (0)

// Kb: [64][128] bf16, A = row*256 + col*2. Fold row low-3 bits into chunk bits.
__device__ __forceinline__ uint32_t kb_swz(uint32_t A) {
    return A ^ (((A >> 8) & 7u) << 4);
}
// Vt: [128][64] bf16, A = d*128 + k*2. Fold d bits so PV read (lanes vary d)
// spreads over 8 chunk slots per 16-lane phase.
__device__ __forceinline__ uint32_t vt_swz(uint32_t A) {
    return A ^ (((A >> 9) & 7u) << 4) ^ (((A >> 8) & 1u) << 6);
}

__global__ __launch_bounds__(256) void sparse_attn_kernel(
    const float* __restrict__ q, const float* __restrict__ k,
    const float* __restrict__ v, float* __restrict__ out)
{
    __shared__ __align__(16) bf16_t Kb[BSZ * DIM];      // 16384 B
    __shared__ __align__(16) bf16_t Vt[DIM * BSZ];      // 16384 B (total 32768)

    // XCD-aware swizzle: 2048 wgs, 8 XCDs -> contiguous 256-chunk per XCD.
    const int L  = ((blockIdx.x & 7) << 8) | (blockIdx.x >> 3);
    const int qi = L & 63;
    const int h  = (L >> 6) & 15;
    const int b  = L >> 10;

    const int tid  = threadIdx.x;
    const int wave = tid >> 6;
    const int lane = tid & 63;
    const int lr = lane & 15;
    const int lk = lane >> 4;
    const int k0 = lk * 8;

    const int krr = tid >> 4;   // K staging: row-in-group 0..15
    const int kc8 = tid & 15;   // K staging: 8-float chunk 0..15
    const int vr  = tid >> 5;   // V staging: 8-row group 0..7
    const int sc4 = tid & 31;   // V staging: float4 column 0..31

    const float scale2 = 0.12751649736230476f;  // (1/sqrt(128)) * log2(e)

    const size_t bh_off = ((size_t)b * SEQ * NH + (size_t)h) * DIM;
    const float* kbh = k + bh_off;
    const float* vbh = v + bh_off;

    // ---- Q fragments, pre-scaled (wave owns q rows [qi*64+wave*16, +16)) ----
    bf16x8 qf[4];
    {
        const float* qrow = q + bh_off + (size_t)(qi * 64 + wave * 16 + lr) * ROWSTRIDE;
        #pragma unroll
        for (int kk = 0; kk < 4; ++kk) {
            const float4 a0 = *(const float4*)(qrow + 32 * kk + k0);
            const float4 a1 = *(const float4*)(qrow + 32 * kk + k0 + 4);
            bf16x8 f;
            f[0] = (bf16_t)(a0.x * scale2); f[1] = (bf16_t)(a0.y * scale2);
            f[2] = (bf16_t)(a0.z * scale2); f[3] = (bf16_t)(a0.w * scale2);
            f[4] = (bf16_t)(a1.x * scale2); f[5] = (bf16_t)(a1.y * scale2);
            f[6] = (bf16_t)(a1.z * scale2); f[7] = (bf16_t)(a1.w * scale2);
            qf[kk] = f;
        }
    }

    f32x4 oacc[8];
    #pragma unroll
    for (int n = 0; n < 8; ++n) oacc[n] = (f32x4){0.f, 0.f, 0.f, 0.f};
    float lrun = 0.f;   // per-lane partial row-sum; this lane's q-row is lr

    const int qrow_local = wave * 16 + lr;  // q position within the 64-block
    const int nnz = (qi < 8) ? (qi + 1) : 9;

    // ---- push-exchange addressing (constant per lane) ----
    const int bit0 = lk & 1;
    const int bit1 = lk >> 1;
    const bool hi  = (lk & 2) != 0;
    const int Dlo  = (lr + 16 * bit1) << 2;   // dest-lane*4, hi_t = 0
    const int Dhi  = Dlo + (32 << 2);         // hi_t = 1
    const int addrA = bit0 ? Dhi : Dlo;       // instrs j = 0,1
    const int addrB = bit0 ? Dlo : Dhi;       // instrs j = 2,3

    float4 kreg[8];   // K row (16i+krr), floats 8*kc8..+7  (pairs per pass)
    float4 vreg[8];   // V rows 8*vr..+7, floats 4*sc4..+3

    #define LOAD_K(jb)                                                            \
    {                                                                             \
        _Pragma("unroll")                                                         \
        for (int i = 0; i < 4; ++i) {                                             \
            const float* p_ = kbh + (size_t)((jb) * 64 + 16 * i + krr) * ROWSTRIDE\
                              + 8 * kc8;                                          \
            kreg[2 * i]     = *(const float4*)(p_);                               \
            kreg[2 * i + 1] = *(const float4*)(p_ + 4);                           \
        }                                                                         \
    }
    #define LOAD_V(jb)                                                            \
    {                                                                             \
        const float* vb_ = vbh + (size_t)((jb) * 64 + 8 * vr) * ROWSTRIDE + 4 * sc4;\
        _Pragma("unroll")                                                         \
        for (int i = 0; i < 8; ++i)                                               \
            vreg[i] = *(const float4*)(vb_ + (size_t)i * ROWSTRIDE);              \
    }

    LOAD_K(0);  // j_of(0) == 0 for every qi
    LOAD_V(0);

    for (int t = 0; t < nnz; ++t) {
        const int j = (qi < 8) ? t : ((t == 0) ? 0 : (qi - 8 + t));
        const int jn = (qi < 8) ? (t + 1) : (qi - 8 + t + 1);
        const bool have_next = (t + 1 < nnz);

        // ---- Kb write from kreg: 4 x b128 (vmcnt waits only the K loads) ----
        #pragma unroll
        for (int i = 0; i < 4; ++i) {
            const float4 a0 = kreg[2 * i];
            const float4 a1 = kreg[2 * i + 1];
            bf16x8 w;
            w[0] = (bf16_t)a0.x; w[1] = (bf16_t)a0.y;
            w[2] = (bf16_t)a0.z; w[3] = (bf16_t)a0.w;
            w[4] = (bf16_t)a1.x; w[5] = (bf16_t)a1.y;
            w[6] = (bf16_t)a1.z; w[7] = (bf16_t)a1.w;
            const uint32_t A = kb_swz((uint32_t)((16 * i + krr) * 256 + 16 * kc8));
            *(bf16x8*)((char*)Kb + A) = w;
        }
        // ---- kreg dead: issue next K loads NOW (full-iter cover) ----
        if (have_next) { LOAD_K(jn); }

        LGKM_BARRIER();   // Kb visible; K(t+1)/V(t) loads stay in flight

        // ---- S^T = K*Q^T: lane holds S[k=16n+4lk+r][q=lr] (exp2 domain) ----
        f32x4 sacc[4];
        __builtin_amdgcn_s_setprio(1);
        #pragma unroll
        for (int n = 0; n < 4; ++n) {
            f32x4 a = (f32x4){0.f, 0.f, 0.f, 0.f};
            #pragma unroll
            for (int kk = 0; kk < 4; ++kk) {
                const uint32_t A = kb_swz((uint32_t)((16 * n + lr) * 256 + 64 * kk + 16 * lk));
                bf16x8 kf = *(const bf16x8*)((const char*)Kb + A);
                a = __builtin_amdgcn_mfma_f32_16x16x32_bf16(kf, qf[kk], a, 0, 0, 0);
            }
            sacc[n] = a;
        }
        __builtin_amdgcn_s_setprio(0);

        // ---- Vt write from vreg: transposed, 4 x b128 (8 contiguous k) ----
        #pragma unroll
        for (int j2 = 0; j2 < 4; ++j2) {
            const int d = 4 * sc4 + j2;
            bf16x8 w;
            w[0] = (bf16_t)((const float*)&vreg[0])[j2];
            w[1] = (bf16_t)((const float*)&vreg[1])[j2];
            w[2] = (bf16_t)((const float*)&vreg[2])[j2];
            w[3] = (bf16_t)((const float*)&vreg[3])[j2];
            w[4] = (bf16_t)((const float*)&vreg[4])[j2];
            w[5] = (bf16_t)((const float*)&vreg[5])[j2];
            w[6] = (bf16_t)((const float*)&vreg[6])[j2];
            w[7] = (bf16_t)((const float*)&vreg[7])[j2];
            const uint32_t A = vt_swz((uint32_t)(d * 128 + 16 * vr));
            *(bf16x8*)((char*)Vt + A) = w;
        }
        // ---- vreg dead: issue next V loads NOW (full-iter cover) ----
        if (have_next) { LOAD_V(jn); }

        // ---- mask (diag only) ----
        if (j == qi) {
            #pragma unroll
            for (int n = 0; n < 4; ++n)
                #pragma unroll
                for (int r = 0; r < 4; ++r) {
                    if (16 * n + 4 * lk + r > qrow_local) sacc[n][r] = -1.0e30f;
                }
        }

        // ---- static-max softmax: p = 2^s directly (scale-invariant) ----
        uint32_t ch[8];
        #pragma unroll
        for (int n = 0; n < 4; ++n) {
            float p0 = exp2f(sacc[n][0]);
            float p1 = exp2f(sacc[n][1]);
            float p2 = exp2f(sacc[n][2]);
            float p3 = exp2f(sacc[n][3]);
            lrun += (p0 + p1) + (p2 + p3);
            bf16x4 c4 = {(bf16_t)p0, (bf16_t)p1, (bf16_t)p2, (bf16_t)p3};
            uint32_t* cw = (uint32_t*)&c4;
            ch[2 * n]     = cw[0];
            ch[2 * n + 1] = cw[1];
        }

        // ---- push-model exchange: paf[kk] = P[q=lr][k=32kk+8lk..+7] ----
        bf16x8 paf[2];
        #pragma unroll
        for (int kk = 0; kk < 2; ++kk) {
            uint32_t r0 = (uint32_t)__builtin_amdgcn_ds_permute(
                addrA, (int)(bit0 ? ch[4 * kk + 2] : ch[4 * kk + 0]));
            uint32_t r1 = (uint32_t)__builtin_amdgcn_ds_permute(
                addrA, (int)(bit0 ? ch[4 * kk + 3] : ch[4 * kk + 1]));
            uint32_t r2 = (uint32_t)__builtin_amdgcn_ds_permute(
                addrB, (int)(bit0 ? ch[4 * kk + 0] : ch[4 * kk + 2]));
            uint32_t r3 = (uint32_t)__builtin_amdgcn_ds_permute(
                addrB, (int)(bit0 ? ch[4 * kk + 1] : ch[4 * kk + 3]));
            u32x4 tv = {hi ? r2 : r0, hi ? r3 : r1,
                        hi ? r0 : r2, hi ? r1 : r3};
            paf[kk] = *(bf16x8*)&tv;
        }

        LGKM_BARRIER();   // Vt visible + this wave's Kb reads done

        // ---- O += P * V ----
        __builtin_amdgcn_s_setprio(1);
        #pragma unroll
        for (int n = 0; n < 8; ++n) {
            f32x4 a = oacc[n];
            #pragma unroll
            for (int kk = 0; kk < 2; ++kk) {
                const uint32_t Av = vt_swz((uint32_t)((16 * n + lr) * 128 + 64 * kk + 16 * lk));
                bf16x8 vf = *(const bf16x8*)((const char*)Vt + Av);
                a = __builtin_amdgcn_mfma_f32_16x16x32_bf16(paf[kk], vf, a, 0, 0, 0);
            }
            oacc[n] = a;
        }
        __builtin_amdgcn_s_setprio(0);
    }

    // ---- epilogue: total l per q-row, redistribute to oacc rows, store ----
    float lrtot = lrun;
    lrtot += __shfl_xor(lrtot, 16);
    lrtot += __shfl_xor(lrtot, 32);
    float* obase = out + bh_off + (size_t)(qi * 64 + wave * 16) * ROWSTRIDE;
    #pragma unroll
    for (int r = 0; r < 4; ++r) {
        const float inv = 1.0f / __shfl(lrtot, 4 * lk + r);
        float* orow = obase + (size_t)(4 * lk + r) * ROWSTRIDE;
        #pragma unroll
        for (int n = 0; n < 8; ++n) {
            orow[16 * n + lr] = oacc[n][r] * inv;
        }
    }
}

extern "C" void kernel_launch(void* const* d_in, const int* in_sizes, int n_in,
                              void* d_out, int out_size, void* d_ws, size_t ws_size,
                              hipStream_t stream) {
    const float* q = (const float*)d_in[0];
    const float* k = (const float*)d_in[1];
    const float* v = (const float*)d_in[2];
    float* out = (float*)d_out;
    sparse_attn_kernel<<<dim3(2048), dim3(256), 0, stream>>>(q, k, v, out);
}

// Round 20
// 95.052 us; speedup vs baseline: 1.0775x; 1.0148x over previous
//
#include <hip/hip_runtime.h>
#include <hip/hip_bf16.h>

// Block-sparse attention: B=2, S=4096, H=16, D=128, BS=64, LOCAL=8, GLOBAL=1.
// fp32 in/out, bf16 MFMA, flash softmax in exp2 domain (static max).
// Round 20 (base r19 = 96.5us): v_cvt_pk_bf16_f32 for all hot fp32->bf16
// conversions. Staging converts 64 scalar casts -> 32 pk ops per thread-iter;
// softmax pack 16 cvt+pack -> 8 pk ops whose u32 results ARE the exchange
// chunks. VALU is the largest measured busy share (30%) and conversion is
// its largest block.

typedef __bf16 bf16_t;
typedef bf16_t bf16x8 __attribute__((ext_vector_type(8)));
typedef float f32x4 __attribute__((ext_vector_type(4)));
typedef uint32_t u32x4 __attribute__((ext_vector_type(4)));

#define BSZ 64
#define DIM 128
#define NH 16
#define SEQ 4096
#define ROWSTRIDE (NH * DIM)

// LDS barrier with lgkm-only drain (global loads may stay in flight).
#define LGKM_BARRIER()                                          \
    do {                                                        \
        asm volatile("s_waitcnt lgkmcnt(0)" ::: "memory");      \
        __builtin_amdgcn_s_barrier();                           \
    } while (0)

// packed f32x2 -> bf16x2 (RNE), result word: low16=lo, high16=hi
__device__ __forceinline__ uint32_t cvt_pk_bf16(float lo, float hi) {
    uint32_t r;
    asm("v_cvt_pk_bf16_f32 %0, %1, %2" : "=v"(r) : "v"(lo), "v"(hi));
    return r;
}

// Kb: [64][128] bf16, A = row*256 + col*2. Fold row low-3 bits into chunk bits.
__device__ __forceinline__ uint32_t kb_swz(uint32_t A) {
    return A ^ (((A >> 8) & 7u) << 4);
}
// Vt: [128][64] bf16, A = d*128 + k*2. Fold d bits so PV read (lanes vary d)
// spreads over 8 chunk slots per 16-lane phase.
__device__ __forceinline__ uint32_t vt_swz(uint32_t A) {
    return A ^ (((A >> 9) & 7u) << 4) ^ (((A >> 8) & 1u) << 6);
}

__global__ __launch_bounds__(256) void sparse_attn_kernel(
    const float* __restrict__ q, const float* __restrict__ k,
    const float* __restrict__ v, float* __restrict__ out)
{
    __shared__ __align__(16) bf16_t Kb[BSZ * DIM];      // 16384 B
    __shared__ __align__(16) bf16_t Vt[DIM * BSZ];      // 16384 B (total 32768)

    // XCD-aware swizzle: 2048 wgs, 8 XCDs -> contiguous 256-chunk per XCD.
    const int L  = ((blockIdx.x & 7) << 8) | (blockIdx.x >> 3);
    const int qi = L & 63;
    const int h  = (L >> 6) & 15;
    const int b  = L >> 10;

    const int tid  = threadIdx.x;
    const int wave = tid >> 6;
    const int lane = tid & 63;
    const int lr = lane & 15;
    const int lk = lane >> 4;
    const int k0 = lk * 8;

    const int krr = tid >> 4;   // K staging: row-in-group 0..15
    const int kc8 = tid & 15;   // K staging: 8-float chunk 0..15
    const int vr  = tid >> 5;   // V staging: 8-row group 0..7
    const int sc4 = tid & 31;   // V staging: float4 column 0..31

    const float scale2 = 0.12751649736230476f;  // (1/sqrt(128)) * log2(e)

    const size_t bh_off = ((size_t)b * SEQ * NH + (size_t)h) * DIM;
    const float* kbh = k + bh_off;
    const float* vbh = v + bh_off;

    // ---- Q fragments, pre-scaled (wave owns q rows [qi*64+wave*16, +16)) ----
    bf16x8 qf[4];
    {
        const float* qrow = q + bh_off + (size_t)(qi * 64 + wave * 16 + lr) * ROWSTRIDE;
        #pragma unroll
        for (int kk = 0; kk < 4; ++kk) {
            const float4 a0 = *(const float4*)(qrow + 32 * kk + k0);
            const float4 a1 = *(const float4*)(qrow + 32 * kk + k0 + 4);
            u32x4 w = {cvt_pk_bf16(a0.x * scale2, a0.y * scale2),
                       cvt_pk_bf16(a0.z * scale2, a0.w * scale2),
                       cvt_pk_bf16(a1.x * scale2, a1.y * scale2),
                       cvt_pk_bf16(a1.z * scale2, a1.w * scale2)};
            qf[kk] = *(bf16x8*)&w;
        }
    }

    f32x4 oacc[8];
    #pragma unroll
    for (int n = 0; n < 8; ++n) oacc[n] = (f32x4){0.f, 0.f, 0.f, 0.f};
    float lrun = 0.f;   // per-lane partial row-sum; this lane's q-row is lr

    const int qrow_local = wave * 16 + lr;  // q position within the 64-block
    const int nnz = (qi < 8) ? (qi + 1) : 9;

    // ---- push-exchange addressing (constant per lane) ----
    const int bit0 = lk & 1;
    const int bit1 = lk >> 1;
    const bool hi  = (lk & 2) != 0;
    const int Dlo  = (lr + 16 * bit1) << 2;   // dest-lane*4, hi_t = 0
    const int Dhi  = Dlo + (32 << 2);         // hi_t = 1
    const int addrA = bit0 ? Dhi : Dlo;       // instrs j = 0,1
    const int addrB = bit0 ? Dlo : Dhi;       // instrs j = 2,3

    float4 kreg[8];   // K row (16i+krr), floats 8*kc8..+7  (pairs per pass)
    float4 vreg[8];   // V rows 8*vr..+7, floats 4*sc4..+3

    #define LOAD_K(jb)                                                            \
    {                                                                             \
        _Pragma("unroll")                                                         \
        for (int i = 0; i < 4; ++i) {                                             \
            const float* p_ = kbh + (size_t)((jb) * 64 + 16 * i + krr) * ROWSTRIDE\
                              + 8 * kc8;                                          \
            kreg[2 * i]     = *(const float4*)(p_);                               \
            kreg[2 * i + 1] = *(const float4*)(p_ + 4);                           \
        }                                                                         \
    }
    #define LOAD_V(jb)                                                            \
    {                                                                             \
        const float* vb_ = vbh + (size_t)((jb) * 64 + 8 * vr) * ROWSTRIDE + 4 * sc4;\
        _Pragma("unroll")                                                         \
        for (int i = 0; i < 8; ++i)                                               \
            vreg[i] = *(const float4*)(vb_ + (size_t)i * ROWSTRIDE);              \
    }

    LOAD_K(0);  // j_of(0) == 0 for every qi
    LOAD_V(0);

    for (int t = 0; t < nnz; ++t) {
        const int j = (qi < 8) ? t : ((t == 0) ? 0 : (qi - 8 + t));
        const int jn = (qi < 8) ? (t + 1) : (qi - 8 + t + 1);
        const bool have_next = (t + 1 < nnz);

        // ---- Kb write from kreg: 4 x b128, cvt_pk converts ----
        #pragma unroll
        for (int i = 0; i < 4; ++i) {
            const float4 a0 = kreg[2 * i];
            const float4 a1 = kreg[2 * i + 1];
            u32x4 w = {cvt_pk_bf16(a0.x, a0.y), cvt_pk_bf16(a0.z, a0.w),
                       cvt_pk_bf16(a1.x, a1.y), cvt_pk_bf16(a1.z, a1.w)};
            const uint32_t A = kb_swz((uint32_t)((16 * i + krr) * 256 + 16 * kc8));
            *(u32x4*)((char*)Kb + A) = w;
        }
        // ---- kreg dead: issue next K loads NOW (full-iter cover) ----
        if (have_next) { LOAD_K(jn); }

        LGKM_BARRIER();   // Kb visible; K(t+1)/V(t) loads stay in flight

        // ---- S^T = K*Q^T: lane holds S[k=16n+4lk+r][q=lr] (exp2 domain) ----
        f32x4 sacc[4];
        __builtin_amdgcn_s_setprio(1);
        #pragma unroll
        for (int n = 0; n < 4; ++n) {
            f32x4 a = (f32x4){0.f, 0.f, 0.f, 0.f};
            #pragma unroll
            for (int kk = 0; kk < 4; ++kk) {
                const uint32_t A = kb_swz((uint32_t)((16 * n + lr) * 256 + 64 * kk + 16 * lk));
                bf16x8 kf = *(const bf16x8*)((const char*)Kb + A);
                a = __builtin_amdgcn_mfma_f32_16x16x32_bf16(kf, qf[kk], a, 0, 0, 0);
            }
            sacc[n] = a;
        }
        __builtin_amdgcn_s_setprio(0);

        // ---- Vt write from vreg: transposed, 4 x b128, cvt_pk converts ----
        #pragma unroll
        for (int j2 = 0; j2 < 4; ++j2) {
            u32x4 w = {cvt_pk_bf16(((const float*)&vreg[0])[j2], ((const float*)&vreg[1])[j2]),
                       cvt_pk_bf16(((const float*)&vreg[2])[j2], ((const float*)&vreg[3])[j2]),
                       cvt_pk_bf16(((const float*)&vreg[4])[j2], ((const float*)&vreg[5])[j2]),
                       cvt_pk_bf16(((const float*)&vreg[6])[j2], ((const float*)&vreg[7])[j2])};
            const int d = 4 * sc4 + j2;
            const uint32_t A = vt_swz((uint32_t)(d * 128 + 16 * vr));
            *(u32x4*)((char*)Vt + A) = w;
        }
        // ---- vreg dead: issue next V loads NOW (full-iter cover) ----
        if (have_next) { LOAD_V(jn); }

        // ---- mask (diag only) ----
        if (j == qi) {
            #pragma unroll
            for (int n = 0; n < 4; ++n)
                #pragma unroll
                for (int r = 0; r < 4; ++r) {
                    if (16 * n + 4 * lk + r > qrow_local) sacc[n][r] = -1.0e30f;
                }
        }

        // ---- static-max softmax: p = 2^s; cvt_pk output IS the chunk word ----
        uint32_t ch[8];
        #pragma unroll
        for (int n = 0; n < 4; ++n) {
            float p0 = exp2f(sacc[n][0]);
            float p1 = exp2f(sacc[n][1]);
            float p2 = exp2f(sacc[n][2]);
            float p3 = exp2f(sacc[n][3]);
            lrun += (p0 + p1) + (p2 + p3);
            ch[2 * n]     = cvt_pk_bf16(p0, p1);
            ch[2 * n + 1] = cvt_pk_bf16(p2, p3);
        }

        // ---- push-model exchange: paf[kk] = P[q=lr][k=32kk+8lk..+7] ----
        bf16x8 paf[2];
        #pragma unroll
        for (int kk = 0; kk < 2; ++kk) {
            uint32_t r0 = (uint32_t)__builtin_amdgcn_ds_permute(
                addrA, (int)(bit0 ? ch[4 * kk + 2] : ch[4 * kk + 0]));
            uint32_t r1 = (uint32_t)__builtin_amdgcn_ds_permute(
                addrA, (int)(bit0 ? ch[4 * kk + 3] : ch[4 * kk + 1]));
            uint32_t r2 = (uint32_t)__builtin_amdgcn_ds_permute(
                addrB, (int)(bit0 ? ch[4 * kk + 0] : ch[4 * kk + 2]));
            uint32_t r3 = (uint32_t)__builtin_amdgcn_ds_permute(
                addrB, (int)(bit0 ? ch[4 * kk + 1] : ch[4 * kk + 3]));
            u32x4 tv = {hi ? r2 : r0, hi ? r3 : r1,
                        hi ? r0 : r2, hi ? r1 : r3};
            paf[kk] = *(bf16x8*)&tv;
        }

        LGKM_BARRIER();   // Vt visible + this wave's Kb reads done

        // ---- O += P * V ----
        __builtin_amdgcn_s_setprio(1);
        #pragma unroll
        for (int n = 0; n < 8; ++n) {
            f32x4 a = oacc[n];
            #pragma unroll
            for (int kk = 0; kk < 2; ++kk) {
                const uint32_t Av = vt_swz((uint32_t)((16 * n + lr) * 128 + 64 * kk + 16 * lk));
                bf16x8 vf = *(const bf16x8*)((const char*)Vt + Av);
                a = __builtin_amdgcn_mfma_f32_16x16x32_bf16(paf[kk], vf, a, 0, 0, 0);
            }
            oacc[n] = a;
        }
        __builtin_amdgcn_s_setprio(0);
    }

    // ---- epilogue: total l per q-row, redistribute to oacc rows, store ----
    float lrtot = lrun;
    lrtot += __shfl_xor(lrtot, 16);
    lrtot += __shfl_xor(lrtot, 32);
    float* obase = out + bh_off + (size_t)(qi * 64 + wave * 16) * ROWSTRIDE;
    #pragma unroll
    for (int r = 0; r < 4; ++r) {
        const float inv = 1.0f / __shfl(lrtot, 4 * lk + r);
        float* orow = obase + (size_t)(4 * lk + r) * ROWSTRIDE;
        #pragma unroll
        for (int n = 0; n < 8; ++n) {
            orow[16 * n + lr] = oacc[n][r] * inv;
        }
    }
}

extern "C" void kernel_launch(void* const* d_in, const int* in_sizes, int n_in,
                              void* d_out, int out_size, void* d_ws, size_t ws_size,
                              hipStream_t stream) {
    const float* q = (const float*)d_in[0];
    const float* k = (const float*)d_in[1];
    const float* v = (const float*)d_in[2];
    float* out = (float*)d_out;
    sparse_attn_kernel<<<dim3(2048), dim3(256), 0, stream>>>(q, k, v, out);
}

// Round 21
// 94.760 us; speedup vs baseline: 1.0808x; 1.0031x over previous
//
#include <hip/hip_runtime.h>
#include <hip/hip_bf16.h>

// Block-sparse attention: B=2, S=4096, H=16, D=128, BS=64, LOCAL=8, GLOBAL=1.
// fp32 in/out, bf16 MFMA, flash softmax in exp2 domain (static max).
// Round 21 (base r20 = 95.05us): remove s_setprio. T5's mechanism needs wave
// role diversity; our 4 waves are barrier-locksteped (m190's GEMM regime,
// where setprio measured NEGATIVE) — prio(1) around MFMA can starve the
// co-resident block's waves, which are our only latency-hiding overlap.

typedef __bf16 bf16_t;
typedef bf16_t bf16x8 __attribute__((ext_vector_type(8)));
typedef float f32x4 __attribute__((ext_vector_type(4)));
typedef uint32_t u32x4 __attribute__((ext_vector_type(4)));

#define BSZ 64
#define DIM 128
#define NH 16
#define SEQ 4096
#define ROWSTRIDE (NH * DIM)

// LDS barrier with lgkm-only drain (global loads may stay in flight).
#define LGKM_BARRIER()                                          \
    do {                                                        \
        asm volatile("s_waitcnt lgkmcnt(0)" ::: "memory");      \
        __builtin_amdgcn_s_barrier();                           \
    } while (0)

// packed f32x2 -> bf16x2 (RNE), result word: low16=lo, high16=hi
__device__ __forceinline__ uint32_t cvt_pk_bf16(float lo, float hi) {
    uint32_t r;
    asm("v_cvt_pk_bf16_f32 %0, %1, %2" : "=v"(r) : "v"(lo), "v"(hi));
    return r;
}

// Kb: [64][128] bf16, A = row*256 + col*2. Fold row low-3 bits into chunk bits.
__device__ __forceinline__ uint32_t kb_swz(uint32_t A) {
    return A ^ (((A >> 8) & 7u) << 4);
}
// Vt: [128][64] bf16, A = d*128 + k*2. Fold d bits so PV read (lanes vary d)
// spreads over 8 chunk slots per 16-lane phase.
__device__ __forceinline__ uint32_t vt_swz(uint32_t A) {
    return A ^ (((A >> 9) & 7u) << 4) ^ (((A >> 8) & 1u) << 6);
}

__global__ __launch_bounds__(256) void sparse_attn_kernel(
    const float* __restrict__ q, const float* __restrict__ k,
    const float* __restrict__ v, float* __restrict__ out)
{
    __shared__ __align__(16) bf16_t Kb[BSZ * DIM];      // 16384 B
    __shared__ __align__(16) bf16_t Vt[DIM * BSZ];      // 16384 B (total 32768)

    // XCD-aware swizzle: 2048 wgs, 8 XCDs -> contiguous 256-chunk per XCD.
    const int L  = ((blockIdx.x & 7) << 8) | (blockIdx.x >> 3);
    const int qi = L & 63;
    const int h  = (L >> 6) & 15;
    const int b  = L >> 10;

    const int tid  = threadIdx.x;
    const int wave = tid >> 6;
    const int lane = tid & 63;
    const int lr = lane & 15;
    const int lk = lane >> 4;
    const int k0 = lk * 8;

    const int krr = tid >> 4;   // K staging: row-in-group 0..15
    const int kc8 = tid & 15;   // K staging: 8-float chunk 0..15
    const int vr  = tid >> 5;   // V staging: 8-row group 0..7
    const int sc4 = tid & 31;   // V staging: float4 column 0..31

    const float scale2 = 0.12751649736230476f;  // (1/sqrt(128)) * log2(e)

    const size_t bh_off = ((size_t)b * SEQ * NH + (size_t)h) * DIM;
    const float* kbh = k + bh_off;
    const float* vbh = v + bh_off;

    // ---- Q fragments, pre-scaled (wave owns q rows [qi*64+wave*16, +16)) ----
    bf16x8 qf[4];
    {
        const float* qrow = q + bh_off + (size_t)(qi * 64 + wave * 16 + lr) * ROWSTRIDE;
        #pragma unroll
        for (int kk = 0; kk < 4; ++kk) {
            const float4 a0 = *(const float4*)(qrow + 32 * kk + k0);
            const float4 a1 = *(const float4*)(qrow + 32 * kk + k0 + 4);
            u32x4 w = {cvt_pk_bf16(a0.x * scale2, a0.y * scale2),
                       cvt_pk_bf16(a0.z * scale2, a0.w * scale2),
                       cvt_pk_bf16(a1.x * scale2, a1.y * scale2),
                       cvt_pk_bf16(a1.z * scale2, a1.w * scale2)};
            qf[kk] = *(bf16x8*)&w;
        }
    }

    f32x4 oacc[8];
    #pragma unroll
    for (int n = 0; n < 8; ++n) oacc[n] = (f32x4){0.f, 0.f, 0.f, 0.f};
    float lrun = 0.f;   // per-lane partial row-sum; this lane's q-row is lr

    const int qrow_local = wave * 16 + lr;  // q position within the 64-block
    const int nnz = (qi < 8) ? (qi + 1) : 9;

    // ---- push-exchange addressing (constant per lane) ----
    const int bit0 = lk & 1;
    const int bit1 = lk >> 1;
    const bool hi  = (lk & 2) != 0;
    const int Dlo  = (lr + 16 * bit1) << 2;   // dest-lane*4, hi_t = 0
    const int Dhi  = Dlo + (32 << 2);         // hi_t = 1
    const int addrA = bit0 ? Dhi : Dlo;       // instrs j = 0,1
    const int addrB = bit0 ? Dlo : Dhi;       // instrs j = 2,3

    float4 kreg[8];   // K row (16i+krr), floats 8*kc8..+7  (pairs per pass)
    float4 vreg[8];   // V rows 8*vr..+7, floats 4*sc4..+3

    #define LOAD_K(jb)                                                            \
    {                                                                             \
        _Pragma("unroll")                                                         \
        for (int i = 0; i < 4; ++i) {                                             \
            const float* p_ = kbh + (size_t)((jb) * 64 + 16 * i + krr) * ROWSTRIDE\
                              + 8 * kc8;                                          \
            kreg[2 * i]     = *(const float4*)(p_);                               \
            kreg[2 * i + 1] = *(const float4*)(p_ + 4);                           \
        }                                                                         \
    }
    #define LOAD_V(jb)                                                            \
    {                                                                             \
        const float* vb_ = vbh + (size_t)((jb) * 64 + 8 * vr) * ROWSTRIDE + 4 * sc4;\
        _Pragma("unroll")                                                         \
        for (int i = 0; i < 8; ++i)                                               \
            vreg[i] = *(const float4*)(vb_ + (size_t)i * ROWSTRIDE);              \
    }

    LOAD_K(0);  // j_of(0) == 0 for every qi
    LOAD_V(0);

    for (int t = 0; t < nnz; ++t) {
        const int j = (qi < 8) ? t : ((t == 0) ? 0 : (qi - 8 + t));
        const int jn = (qi < 8) ? (t + 1) : (qi - 8 + t + 1);
        const bool have_next = (t + 1 < nnz);

        // ---- Kb write from kreg: 4 x b128, cvt_pk converts ----
        #pragma unroll
        for (int i = 0; i < 4; ++i) {
            const float4 a0 = kreg[2 * i];
            const float4 a1 = kreg[2 * i + 1];
            u32x4 w = {cvt_pk_bf16(a0.x, a0.y), cvt_pk_bf16(a0.z, a0.w),
                       cvt_pk_bf16(a1.x, a1.y), cvt_pk_bf16(a1.z, a1.w)};
            const uint32_t A = kb_swz((uint32_t)((16 * i + krr) * 256 + 16 * kc8));
            *(u32x4*)((char*)Kb + A) = w;
        }
        // ---- kreg dead: issue next K loads NOW (full-iter cover) ----
        if (have_next) { LOAD_K(jn); }

        LGKM_BARRIER();   // Kb visible; K(t+1)/V(t) loads stay in flight

        // ---- S^T = K*Q^T: lane holds S[k=16n+4lk+r][q=lr] (exp2 domain) ----
        f32x4 sacc[4];
        #pragma unroll
        for (int n = 0; n < 4; ++n) {
            f32x4 a = (f32x4){0.f, 0.f, 0.f, 0.f};
            #pragma unroll
            for (int kk = 0; kk < 4; ++kk) {
                const uint32_t A = kb_swz((uint32_t)((16 * n + lr) * 256 + 64 * kk + 16 * lk));
                bf16x8 kf = *(const bf16x8*)((const char*)Kb + A);
                a = __builtin_amdgcn_mfma_f32_16x16x32_bf16(kf, qf[kk], a, 0, 0, 0);
            }
            sacc[n] = a;
        }

        // ---- Vt write from vreg: transposed, 4 x b128, cvt_pk converts ----
        #pragma unroll
        for (int j2 = 0; j2 < 4; ++j2) {
            u32x4 w = {cvt_pk_bf16(((const float*)&vreg[0])[j2], ((const float*)&vreg[1])[j2]),
                       cvt_pk_bf16(((const float*)&vreg[2])[j2], ((const float*)&vreg[3])[j2]),
                       cvt_pk_bf16(((const float*)&vreg[4])[j2], ((const float*)&vreg[5])[j2]),
                       cvt_pk_bf16(((const float*)&vreg[6])[j2], ((const float*)&vreg[7])[j2])};
            const int d = 4 * sc4 + j2;
            const uint32_t A = vt_swz((uint32_t)(d * 128 + 16 * vr));
            *(u32x4*)((char*)Vt + A) = w;
        }
        // ---- vreg dead: issue next V loads NOW (full-iter cover) ----
        if (have_next) { LOAD_V(jn); }

        // ---- mask (diag only) ----
        if (j == qi) {
            #pragma unroll
            for (int n = 0; n < 4; ++n)
                #pragma unroll
                for (int r = 0; r < 4; ++r) {
                    if (16 * n + 4 * lk + r > qrow_local) sacc[n][r] = -1.0e30f;
                }
        }

        // ---- static-max softmax: p = 2^s; cvt_pk output IS the chunk word ----
        uint32_t ch[8];
        #pragma unroll
        for (int n = 0; n < 4; ++n) {
            float p0 = exp2f(sacc[n][0]);
            float p1 = exp2f(sacc[n][1]);
            float p2 = exp2f(sacc[n][2]);
            float p3 = exp2f(sacc[n][3]);
            lrun += (p0 + p1) + (p2 + p3);
            ch[2 * n]     = cvt_pk_bf16(p0, p1);
            ch[2 * n + 1] = cvt_pk_bf16(p2, p3);
        }

        // ---- push-model exchange: paf[kk] = P[q=lr][k=32kk+8lk..+7] ----
        bf16x8 paf[2];
        #pragma unroll
        for (int kk = 0; kk < 2; ++kk) {
            uint32_t r0 = (uint32_t)__builtin_amdgcn_ds_permute(
                addrA, (int)(bit0 ? ch[4 * kk + 2] : ch[4 * kk + 0]));
            uint32_t r1 = (uint32_t)__builtin_amdgcn_ds_permute(
                addrA, (int)(bit0 ? ch[4 * kk + 3] : ch[4 * kk + 1]));
            uint32_t r2 = (uint32_t)__builtin_amdgcn_ds_permute(
                addrB, (int)(bit0 ? ch[4 * kk + 0] : ch[4 * kk + 2]));
            uint32_t r3 = (uint32_t)__builtin_amdgcn_ds_permute(
                addrB, (int)(bit0 ? ch[4 * kk + 1] : ch[4 * kk + 3]));
            u32x4 tv = {hi ? r2 : r0, hi ? r3 : r1,
                        hi ? r0 : r2, hi ? r1 : r3};
            paf[kk] = *(bf16x8*)&tv;
        }

        LGKM_BARRIER();   // Vt visible + this wave's Kb reads done

        // ---- O += P * V ----
        #pragma unroll
        for (int n = 0; n < 8; ++n) {
            f32x4 a = oacc[n];
            #pragma unroll
            for (int kk = 0; kk < 2; ++kk) {
                const uint32_t Av = vt_swz((uint32_t)((16 * n + lr) * 128 + 64 * kk + 16 * lk));
                bf16x8 vf = *(const bf16x8*)((const char*)Vt + Av);
                a = __builtin_amdgcn_mfma_f32_16x16x32_bf16(paf[kk], vf, a, 0, 0, 0);
            }
            oacc[n] = a;
        }
    }

    // ---- epilogue: total l per q-row, redistribute to oacc rows, store ----
    float lrtot = lrun;
    lrtot += __shfl_xor(lrtot, 16);
    lrtot += __shfl_xor(lrtot, 32);
    float* obase = out + bh_off + (size_t)(qi * 64 + wave * 16) * ROWSTRIDE;
    #pragma unroll
    for (int r = 0; r < 4; ++r) {
        const float inv = 1.0f / __shfl(lrtot, 4 * lk + r);
        float* orow = obase + (size_t)(4 * lk + r) * ROWSTRIDE;
        #pragma unroll
        for (int n = 0; n < 8; ++n) {
            orow[16 * n + lr] = oacc[n][r] * inv;
        }
    }
}

extern "C" void kernel_launch(void* const* d_in, const int* in_sizes, int n_in,
                              void* d_out, int out_size, void* d_ws, size_t ws_size,
                              hipStream_t stream) {
    const float* q = (const float*)d_in[0];
    const float* k = (const float*)d_in[1];
    const float* v = (const float*)d_in[2];
    float* out = (float*)d_out;
    sparse_attn_kernel<<<dim3(2048), dim3(256), 0, stream>>>(q, k, v, out);
}

// Round 22
// 92.276 us; speedup vs baseline: 1.1099x; 1.0269x over previous
//
#include <hip/hip_runtime.h>
#include <hip/hip_bf16.h>

// Block-sparse attention: B=2, S=4096, H=16, D=128, BS=64, LOCAL=8, GLOBAL=1.
// fp32 in/out, bf16 MFMA, flash softmax in exp2 domain (static max).
// Round 22 (base r21 = 94.76us): rank-5 swizzles. GF(2) audit showed QK reads
// and PV reads were BOTH 4-way bank-conflicted (slot functions rank 4: kb's
// slot bit3 was a per-instr const, vt's bit2 reused lr1). New terms fold the
// missing independent lane bits -> all four LDS access patterns exactly 2-way
// (free per m136). Bijective (XOR sources >= bit8 > targets), same function at
// write and read -> math unchanged.

typedef __bf16 bf16_t;
typedef bf16_t bf16x8 __attribute__((ext_vector_type(8)));
typedef float f32x4 __attribute__((ext_vector_type(4)));
typedef uint32_t u32x4 __attribute__((ext_vector_type(4)));

#define BSZ 64
#define DIM 128
#define NH 16
#define SEQ 4096
#define ROWSTRIDE (NH * DIM)

// LDS barrier with lgkm-only drain (global loads may stay in flight).
#define LGKM_BARRIER()                                          \
    do {                                                        \
        asm volatile("s_waitcnt lgkmcnt(0)" ::: "memory");      \
        __builtin_amdgcn_s_barrier();                           \
    } while (0)

// packed f32x2 -> bf16x2 (RNE), result word: low16=lo, high16=hi
__device__ __forceinline__ uint32_t cvt_pk_bf16(float lo, float hi) {
    uint32_t r;
    asm("v_cvt_pk_bf16_f32 %0, %1, %2" : "=v"(r) : "v"(lo), "v"(hi));
    return r;
}

// Kb: [64][128] bf16, A = row*256 + col*2.
// slot bits: {lk0^lr0, lk1^lr1, kk0^lr2, kk1^lr3, lr0} -> rank 5 (2-way).
__device__ __forceinline__ uint32_t kb_swz(uint32_t A) {
    return A ^ (((A >> 8) & 7u) << 4) ^ (((A >> 11) & 1u) << 7);
}
// Vt: [128][64] bf16, A = d*128 + k*2.
// read slot: {lr0, lr1, lk0^lr2, lk1^lr3, lr2} rank 5; write slot gets sc4
// bits 0-4 spread over all 5 slot bits -> both 2-way.
__device__ __forceinline__ uint32_t vt_swz(uint32_t A) {
    return A ^ (((A >> 9) & 7u) << 4) ^ (((A >> 9) & 1u) << 6) ^ (((A >> 12) & 3u) << 7);
}

__global__ __launch_bounds__(256) void sparse_attn_kernel(
    const float* __restrict__ q, const float* __restrict__ k,
    const float* __restrict__ v, float* __restrict__ out)
{
    __shared__ __align__(16) bf16_t Kb[BSZ * DIM];      // 16384 B
    __shared__ __align__(16) bf16_t Vt[DIM * BSZ];      // 16384 B (total 32768)

    // XCD-aware swizzle: 2048 wgs, 8 XCDs -> contiguous 256-chunk per XCD.
    const int L  = ((blockIdx.x & 7) << 8) | (blockIdx.x >> 3);
    const int qi = L & 63;
    const int h  = (L >> 6) & 15;
    const int b  = L >> 10;

    const int tid  = threadIdx.x;
    const int wave = tid >> 6;
    const int lane = tid & 63;
    const int lr = lane & 15;
    const int lk = lane >> 4;
    const int k0 = lk * 8;

    const int krr = tid >> 4;   // K staging: row-in-group 0..15
    const int kc8 = tid & 15;   // K staging: 8-float chunk 0..15
    const int vr  = tid >> 5;   // V staging: 8-row group 0..7
    const int sc4 = tid & 31;   // V staging: float4 column 0..31

    const float scale2 = 0.12751649736230476f;  // (1/sqrt(128)) * log2(e)

    const size_t bh_off = ((size_t)b * SEQ * NH + (size_t)h) * DIM;
    const float* kbh = k + bh_off;
    const float* vbh = v + bh_off;

    // ---- Q fragments, pre-scaled (wave owns q rows [qi*64+wave*16, +16)) ----
    bf16x8 qf[4];
    {
        const float* qrow = q + bh_off + (size_t)(qi * 64 + wave * 16 + lr) * ROWSTRIDE;
        #pragma unroll
        for (int kk = 0; kk < 4; ++kk) {
            const float4 a0 = *(const float4*)(qrow + 32 * kk + k0);
            const float4 a1 = *(const float4*)(qrow + 32 * kk + k0 + 4);
            u32x4 w = {cvt_pk_bf16(a0.x * scale2, a0.y * scale2),
                       cvt_pk_bf16(a0.z * scale2, a0.w * scale2),
                       cvt_pk_bf16(a1.x * scale2, a1.y * scale2),
                       cvt_pk_bf16(a1.z * scale2, a1.w * scale2)};
            qf[kk] = *(bf16x8*)&w;
        }
    }

    f32x4 oacc[8];
    #pragma unroll
    for (int n = 0; n < 8; ++n) oacc[n] = (f32x4){0.f, 0.f, 0.f, 0.f};
    float lrun = 0.f;   // per-lane partial row-sum; this lane's q-row is lr

    const int qrow_local = wave * 16 + lr;  // q position within the 64-block
    const int nnz = (qi < 8) ? (qi + 1) : 9;

    // ---- push-exchange addressing (constant per lane) ----
    const int bit0 = lk & 1;
    const int bit1 = lk >> 1;
    const bool hi  = (lk & 2) != 0;
    const int Dlo  = (lr + 16 * bit1) << 2;   // dest-lane*4, hi_t = 0
    const int Dhi  = Dlo + (32 << 2);         // hi_t = 1
    const int addrA = bit0 ? Dhi : Dlo;       // instrs j = 0,1
    const int addrB = bit0 ? Dlo : Dhi;       // instrs j = 2,3

    float4 kreg[8];   // K row (16i+krr), floats 8*kc8..+7  (pairs per pass)
    float4 vreg[8];   // V rows 8*vr..+7, floats 4*sc4..+3

    #define LOAD_K(jb)                                                            \
    {                                                                             \
        _Pragma("unroll")                                                         \
        for (int i = 0; i < 4; ++i) {                                             \
            const float* p_ = kbh + (size_t)((jb) * 64 + 16 * i + krr) * ROWSTRIDE\
                              + 8 * kc8;                                          \
            kreg[2 * i]     = *(const float4*)(p_);                               \
            kreg[2 * i + 1] = *(const float4*)(p_ + 4);                           \
        }                                                                         \
    }
    #define LOAD_V(jb)                                                            \
    {                                                                             \
        const float* vb_ = vbh + (size_t)((jb) * 64 + 8 * vr) * ROWSTRIDE + 4 * sc4;\
        _Pragma("unroll")                                                         \
        for (int i = 0; i < 8; ++i)                                               \
            vreg[i] = *(const float4*)(vb_ + (size_t)i * ROWSTRIDE);              \
    }

    LOAD_K(0);  // j_of(0) == 0 for every qi
    LOAD_V(0);

    for (int t = 0; t < nnz; ++t) {
        const int j = (qi < 8) ? t : ((t == 0) ? 0 : (qi - 8 + t));
        const int jn = (qi < 8) ? (t + 1) : (qi - 8 + t + 1);
        const bool have_next = (t + 1 < nnz);

        // ---- Kb write from kreg: 4 x b128, cvt_pk converts ----
        #pragma unroll
        for (int i = 0; i < 4; ++i) {
            const float4 a0 = kreg[2 * i];
            const float4 a1 = kreg[2 * i + 1];
            u32x4 w = {cvt_pk_bf16(a0.x, a0.y), cvt_pk_bf16(a0.z, a0.w),
                       cvt_pk_bf16(a1.x, a1.y), cvt_pk_bf16(a1.z, a1.w)};
            const uint32_t A = kb_swz((uint32_t)((16 * i + krr) * 256 + 16 * kc8));
            *(u32x4*)((char*)Kb + A) = w;
        }
        // ---- kreg dead: issue next K loads NOW (full-iter cover) ----
        if (have_next) { LOAD_K(jn); }

        LGKM_BARRIER();   // Kb visible; K(t+1)/V(t) loads stay in flight

        // ---- S^T = K*Q^T: lane holds S[k=16n+4lk+r][q=lr] (exp2 domain) ----
        f32x4 sacc[4];
        #pragma unroll
        for (int n = 0; n < 4; ++n) {
            f32x4 a = (f32x4){0.f, 0.f, 0.f, 0.f};
            #pragma unroll
            for (int kk = 0; kk < 4; ++kk) {
                const uint32_t A = kb_swz((uint32_t)((16 * n + lr) * 256 + 64 * kk + 16 * lk));
                bf16x8 kf = *(const bf16x8*)((const char*)Kb + A);
                a = __builtin_amdgcn_mfma_f32_16x16x32_bf16(kf, qf[kk], a, 0, 0, 0);
            }
            sacc[n] = a;
        }

        // ---- Vt write from vreg: transposed, 4 x b128, cvt_pk converts ----
        #pragma unroll
        for (int j2 = 0; j2 < 4; ++j2) {
            u32x4 w = {cvt_pk_bf16(((const float*)&vreg[0])[j2], ((const float*)&vreg[1])[j2]),
                       cvt_pk_bf16(((const float*)&vreg[2])[j2], ((const float*)&vreg[3])[j2]),
                       cvt_pk_bf16(((const float*)&vreg[4])[j2], ((const float*)&vreg[5])[j2]),
                       cvt_pk_bf16(((const float*)&vreg[6])[j2], ((const float*)&vreg[7])[j2])};
            const int d = 4 * sc4 + j2;
            const uint32_t A = vt_swz((uint32_t)(d * 128 + 16 * vr));
            *(u32x4*)((char*)Vt + A) = w;
        }
        // ---- vreg dead: issue next V loads NOW (full-iter cover) ----
        if (have_next) { LOAD_V(jn); }

        // ---- mask (diag only) ----
        if (j == qi) {
            #pragma unroll
            for (int n = 0; n < 4; ++n)
                #pragma unroll
                for (int r = 0; r < 4; ++r) {
                    if (16 * n + 4 * lk + r > qrow_local) sacc[n][r] = -1.0e30f;
                }
        }

        // ---- static-max softmax: p = 2^s; cvt_pk output IS the chunk word ----
        uint32_t ch[8];
        #pragma unroll
        for (int n = 0; n < 4; ++n) {
            float p0 = exp2f(sacc[n][0]);
            float p1 = exp2f(sacc[n][1]);
            float p2 = exp2f(sacc[n][2]);
            float p3 = exp2f(sacc[n][3]);
            lrun += (p0 + p1) + (p2 + p3);
            ch[2 * n]     = cvt_pk_bf16(p0, p1);
            ch[2 * n + 1] = cvt_pk_bf16(p2, p3);
        }

        // ---- push-model exchange: paf[kk] = P[q=lr][k=32kk+8lk..+7] ----
        bf16x8 paf[2];
        #pragma unroll
        for (int kk = 0; kk < 2; ++kk) {
            uint32_t r0 = (uint32_t)__builtin_amdgcn_ds_permute(
                addrA, (int)(bit0 ? ch[4 * kk + 2] : ch[4 * kk + 0]));
            uint32_t r1 = (uint32_t)__builtin_amdgcn_ds_permute(
                addrA, (int)(bit0 ? ch[4 * kk + 3] : ch[4 * kk + 1]));
            uint32_t r2 = (uint32_t)__builtin_amdgcn_ds_permute(
                addrB, (int)(bit0 ? ch[4 * kk + 0] : ch[4 * kk + 2]));
            uint32_t r3 = (uint32_t)__builtin_amdgcn_ds_permute(
                addrB, (int)(bit0 ? ch[4 * kk + 1] : ch[4 * kk + 3]));
            u32x4 tv = {hi ? r2 : r0, hi ? r3 : r1,
                        hi ? r0 : r2, hi ? r1 : r3};
            paf[kk] = *(bf16x8*)&tv;
        }

        LGKM_BARRIER();   // Vt visible + this wave's Kb reads done

        // ---- O += P * V ----
        #pragma unroll
        for (int n = 0; n < 8; ++n) {
            f32x4 a = oacc[n];
            #pragma unroll
            for (int kk = 0; kk < 2; ++kk) {
                const uint32_t Av = vt_swz((uint32_t)((16 * n + lr) * 128 + 64 * kk + 16 * lk));
                bf16x8 vf = *(const bf16x8*)((const char*)Vt + Av);
                a = __builtin_amdgcn_mfma_f32_16x16x32_bf16(paf[kk], vf, a, 0, 0, 0);
            }
            oacc[n] = a;
        }
    }

    // ---- epilogue: total l per q-row, redistribute to oacc rows, store ----
    float lrtot = lrun;
    lrtot += __shfl_xor(lrtot, 16);
    lrtot += __shfl_xor(lrtot, 32);
    float* obase = out + bh_off + (size_t)(qi * 64 + wave * 16) * ROWSTRIDE;
    #pragma unroll
    for (int r = 0; r < 4; ++r) {
        const float inv = 1.0f / __shfl(lrtot, 4 * lk + r);
        float* orow = obase + (size_t)(4 * lk + r) * ROWSTRIDE;
        #pragma unroll
        for (int n = 0; n < 8; ++n) {
            orow[16 * n + lr] = oacc[n][r] * inv;
        }
    }
}

extern "C" void kernel_launch(void* const* d_in, const int* in_sizes, int n_in,
                              void* d_out, int out_size, void* d_ws, size_t ws_size,
                              hipStream_t stream) {
    const float* q = (const float*)d_in[0];
    const float* k = (const float*)d_in[1];
    const float* v = (const float*)d_in[2];
    float* out = (float*)d_out;
    sparse_attn_kernel<<<dim3(2048), dim3(256), 0, stream>>>(q, k, v, out);
}